// Round 1
// baseline (328.158 us; speedup 1.0000x reference)
//
#include <hip/hip_runtime.h>
#include <hip/hip_fp16.h>

// Problem: TQ=2, TK=5, B=16384, D=512, fp32 in/out.
// Algebra: out = h@Wd1 + (softmax(h@M@e^T)@e)@W2,  M=Wq@Wk^T, W2=Wv@Wd2.
// MFMA GEMMs in fp16 (bf16 logits would break softmax vs 0.108 absmax thr),
// logits/softmax/att@e in fp32 VALU.

#define B_TOT   16384
#define DDIM    512
#define TQn     2
#define TKn     5
#define NBATCH  32
#define ROWS    64           // 2*NBATCH rows per block
#define THREADS 512
#define NWAVE   8

typedef _Float16 f16;
typedef _Float16 f16x8 __attribute__((ext_vector_type(8)));
typedef _Float16 f16x4 __attribute__((ext_vector_type(4)));
typedef float    f32x4 __attribute__((ext_vector_type(4)));

#define LDS_A_BYTES 131072                       // 64 rows x 1024 f16 (2048B/row)
#define LDS_TOTAL   (LDS_A_BYTES + NWAVE * 4096) // + 8 wave-private B slices = 163840

// A-region swizzle: XOR bits 4-6 of the in-row byte offset with row&7.
// Breaks the 16-way bank conflict of stride-2048B fragment reads (G4/T2).
__device__ __forceinline__ int swzA(int row, int off) { return off ^ ((row & 7) << 4); }
// B-slice rows are 64B (only bits 4-5 free): 2-bit XOR -> reads conflict-free, writes 4-way.
__device__ __forceinline__ int swzB(int nl, int off)  { return off ^ (((nl >> 1) & 3) << 4); }

// One K-step (Kt=32) of a wave-private-slice GEMM:
//  write prefetched B tile -> LDS slice, prefetch tile KT+2 -> regs,
//  read A/B fragments, 16x MFMA. No __syncthreads (slice is wave-private;
//  per-wave LDS ops are processed in order).
#define GSTEP(BREG, KT, SRC, SHIFT, NITER, ACC)                                   \
  {                                                                               \
    _Pragma("unroll")                                                             \
    for (int i = 0; i < 4; ++i) {                                                 \
      int nl  = (i << 4) + (lane >> 2);                                           \
      int k16 = lane & 3;                                                         \
      *reinterpret_cast<uint4*>(bbase + nl * 64 + swzB(nl, k16 << 4)) = BREG[i];  \
    }                                                                             \
    if ((KT) + 2 < (NITER)) {                                                     \
      _Pragma("unroll")                                                           \
      for (int i = 0; i < 4; ++i) {                                               \
        int nl  = (i << 4) + (lane >> 2);                                         \
        int k16 = lane & 3;                                                       \
        BREG[i] = *reinterpret_cast<const uint4*>(                                \
            SRC + ((size_t)(64 * w + nl) << (SHIFT)) + ((KT) + 2) * 32 + (k16 << 3)); \
      }                                                                           \
    }                                                                             \
    f16x8 af[4], bf[4];                                                           \
    _Pragma("unroll")                                                             \
    for (int fm = 0; fm < 4; ++fm) {                                              \
      int row = (fm << 4) + l15;                                                  \
      af[fm] = *reinterpret_cast<const f16x8*>(                                   \
          abase + row * 2048 + swzA(row, (KT) * 64 + (g << 4)));                  \
    }                                                                             \
    _Pragma("unroll")                                                             \
    for (int fn = 0; fn < 4; ++fn) {                                              \
      int nl = (fn << 4) + l15;                                                   \
      bf[fn] = *reinterpret_cast<const f16x8*>(bbase + nl * 64 + swzB(nl, g << 4)); \
    }                                                                             \
    _Pragma("unroll")                                                             \
    for (int fm = 0; fm < 4; ++fm)                                                \
      _Pragma("unroll")                                                           \
      for (int fn = 0; fn < 4; ++fn)                                              \
        ACC[fm][fn] = __builtin_amdgcn_mfma_f32_16x16x32_f16(af[fm], bf[fn],      \
                                                             ACC[fm][fn], 0, 0, 0); \
  }

__global__ __launch_bounds__(THREADS, 2) void fused_attn(
    const float* __restrict__ hptr, const float* __restrict__ eptr,
    const f16* __restrict__ Mt, const f16* __restrict__ Wdt,
    float* __restrict__ outp)
{
  extern __shared__ char smem[];
  const int tid  = threadIdx.x;
  const int lane = tid & 63;
  const int w    = tid >> 6;
  const int g    = lane >> 4;
  const int l15  = lane & 15;
  const int b0   = blockIdx.x * NBATCH;
  char* const abase = smem;
  char* const bbase = smem + LDS_A_BYTES + w * 4096;

  // ---- stage H (fp32 global -> f16 LDS, A[row][k<512]) ----
  #pragma unroll
  for (int i = 0; i < 16; ++i) {
    int c   = tid + THREADS * i;           // 8192 chunks of 4 floats
    int row = c >> 7;
    int k4  = c & 127;
    int tq  = row & 1;
    int b   = b0 + (row >> 1);
    const float4 v = *reinterpret_cast<const float4*>(
        hptr + ((size_t)(tq * B_TOT + b) << 9) + (k4 << 2));
    f16x4 p;
    p[0] = (f16)v.x; p[1] = (f16)v.y; p[2] = (f16)v.z; p[3] = (f16)v.w;
    *reinterpret_cast<f16x4*>(abase + row * 2048 + swzA(row, k4 << 3)) = p;
  }

  // ---- GEMM1 prologue: prefetch M tiles kt=0,1 ----
  uint4 ba[4], bb[4];
  #pragma unroll
  for (int i = 0; i < 4; ++i) {
    int nl  = (i << 4) + (lane >> 2);
    int k16 = lane & 3;
    ba[i] = *reinterpret_cast<const uint4*>(Mt + ((size_t)(64 * w + nl) << 9) + (k16 << 3));
    bb[i] = *reinterpret_cast<const uint4*>(Mt + ((size_t)(64 * w + nl) << 9) + 32 + (k16 << 3));
  }
  __syncthreads();   // H staged

  // ---- GEMM1: T[64x512] = H @ M  (wave owns cols 64w..64w+63) ----
  f32x4 acc[4][4];
  #pragma unroll
  for (int fm = 0; fm < 4; ++fm)
    #pragma unroll
    for (int fn = 0; fn < 4; ++fn)
      acc[fm][fn] = (f32x4){0.f, 0.f, 0.f, 0.f};
  for (int kt = 0; kt < 16; kt += 2) {
    GSTEP(ba, kt,     Mt, 9, 16, acc);
    GSTEP(bb, kt + 1, Mt, 9, 16, acc);
  }

  // ---- T -> LDS f16 (A[row][512+n]); C/D map: row=(lane>>4)*4+reg, col=lane&15 ----
  #pragma unroll
  for (int fm = 0; fm < 4; ++fm)
    #pragma unroll
    for (int fn = 0; fn < 4; ++fn)
      #pragma unroll
      for (int r = 0; r < 4; ++r) {
        int row = (fm << 4) + (g << 2) + r;
        int n   = (w << 6) + (fn << 4) + l15;
        *reinterpret_cast<f16*>(abase + row * 2048 + swzA(row, 1024 + (n << 1))) =
            (f16)acc[fm][fn][r];
      }

  // GEMM2 prologue loads issued early (hide L2 latency under softmax phase)
  #pragma unroll
  for (int i = 0; i < 4; ++i) {
    int nl  = (i << 4) + (lane >> 2);
    int k16 = lane & 3;
    ba[i] = *reinterpret_cast<const uint4*>(Wdt + ((size_t)(64 * w + nl) << 10) + (k16 << 3));
    bb[i] = *reinterpret_cast<const uint4*>(Wdt + ((size_t)(64 * w + nl) << 10) + 32 + (k16 << 3));
  }
  __syncthreads();   // all T visible

  // ---- softmax + u = att@e (fp32), wave handles batches 4w..4w+3 ----
  for (int bi = 0; bi < 4; ++bi) {
    const int bl = (w << 2) + bi;
    const int b  = b0 + bl;
    float ev[TKn][8];
    #pragma unroll
    for (int j = 0; j < TKn; ++j) {
      const float4* p = reinterpret_cast<const float4*>(
          eptr + ((size_t)(j * B_TOT + b) << 9) + (lane << 3));
      float4 u0 = p[0], u1 = p[1];
      ev[j][0] = u0.x; ev[j][1] = u0.y; ev[j][2] = u0.z; ev[j][3] = u0.w;
      ev[j][4] = u1.x; ev[j][5] = u1.y; ev[j][6] = u1.z; ev[j][7] = u1.w;
    }
    float tv[TQn][8];
    #pragma unroll
    for (int i = 0; i < TQn; ++i) {
      int row = (bl << 1) + i;
      f16x8 tf = *reinterpret_cast<const f16x8*>(
          abase + row * 2048 + swzA(row, 1024 + (lane << 4)));
      #pragma unroll
      for (int m = 0; m < 8; ++m) tv[i][m] = (float)tf[m];
    }
    float att[TQn][TKn];
    #pragma unroll
    for (int i = 0; i < TQn; ++i)
      #pragma unroll
      for (int j = 0; j < TKn; ++j) {
        float s = 0.f;
        #pragma unroll
        for (int m = 0; m < 8; ++m) s += tv[i][m] * ev[j][m];
        #pragma unroll
        for (int d = 1; d < 64; d <<= 1) s += __shfl_xor(s, d, 64);
        att[i][j] = s;
      }
    #pragma unroll
    for (int i = 0; i < TQn; ++i) {
      float mx = att[i][0];
      #pragma unroll
      for (int j = 1; j < TKn; ++j) mx = fmaxf(mx, att[i][j]);
      float sum = 0.f;
      #pragma unroll
      for (int j = 0; j < TKn; ++j) { float pv = __expf(att[i][j] - mx); att[i][j] = pv; sum += pv; }
      float rs = 1.0f / sum;
      #pragma unroll
      for (int j = 0; j < TKn; ++j) att[i][j] *= rs;
    }
    #pragma unroll
    for (int i = 0; i < TQn; ++i) {
      int row = (bl << 1) + i;
      f16x8 uv;
      #pragma unroll
      for (int m = 0; m < 8; ++m) {
        float s = 0.f;
        #pragma unroll
        for (int j = 0; j < TKn; ++j) s += att[i][j] * ev[j][m];
        uv[m] = (f16)s;
      }
      *reinterpret_cast<f16x8*>(abase + row * 2048 + swzA(row, 1024 + (lane << 4))) = uv;
    }
  }
  __syncthreads();   // all U visible

  // ---- GEMM2: OUT[64x512] = [H|U] @ Wdown'_t  (K=1024) ----
  f32x4 acc2[4][4];
  #pragma unroll
  for (int fm = 0; fm < 4; ++fm)
    #pragma unroll
    for (int fn = 0; fn < 4; ++fn)
      acc2[fm][fn] = (f32x4){0.f, 0.f, 0.f, 0.f};
  for (int kt = 0; kt < 32; kt += 2) {
    GSTEP(ba, kt,     Wdt, 10, 32, acc2);
    GSTEP(bb, kt + 1, Wdt, 10, 32, acc2);
  }

  // ---- epilogue: fp32 store, out[tq][b][col] ----
  #pragma unroll
  for (int fm = 0; fm < 4; ++fm)
    #pragma unroll
    for (int fn = 0; fn < 4; ++fn)
      #pragma unroll
      for (int r = 0; r < 4; ++r) {
        int row = (fm << 4) + (g << 2) + r;
        int col = (w << 6) + (fn << 4) + l15;
        int tq  = row & 1;
        int b   = b0 + (row >> 1);
        outp[((size_t)(tq * B_TOT + b) << 9) + col] = acc2[fm][fn][r];
      }
}

// ---- prep: M_t[n][k] = sum_e Wq[k][e]*Wk[n][e]  (f16, N-major for B-operand) ----
__global__ __launch_bounds__(256) void prep_mt(const float* __restrict__ Wq,
                                               const float* __restrict__ Wk,
                                               f16* __restrict__ Mt) {
  __shared__ float qs[32][68];
  __shared__ float ks[32][68];
  const int tid = threadIdx.x;
  const int n0 = (blockIdx.x & 15) << 5;
  const int k0 = (blockIdx.x >> 4) << 5;
  float accv[4] = {0.f, 0.f, 0.f, 0.f};
  for (int e0 = 0; e0 < 512; e0 += 64) {
    #pragma unroll
    for (int i = 0; i < 2; ++i) {
      int c = tid + (i << 8);
      int r = c >> 4;
      int e4 = (c & 15) << 2;
      *reinterpret_cast<float4*>(&qs[r][e4]) =
          *reinterpret_cast<const float4*>(Wq + ((k0 + r) << 9) + e0 + e4);
      *reinterpret_cast<float4*>(&ks[r][e4]) =
          *reinterpret_cast<const float4*>(Wk + ((n0 + r) << 9) + e0 + e4);
    }
    __syncthreads();
    #pragma unroll
    for (int i = 0; i < 4; ++i) {
      int o = tid + (i << 8);
      int nl = o >> 5, kl = o & 31;
      float s = accv[i];
      #pragma unroll
      for (int e = 0; e < 64; e += 4) {
        float4 a  = *reinterpret_cast<const float4*>(&qs[kl][e]);
        float4 bq = *reinterpret_cast<const float4*>(&ks[nl][e]);
        s += a.x * bq.x + a.y * bq.y + a.z * bq.z + a.w * bq.w;
      }
      accv[i] = s;
    }
    __syncthreads();
  }
  #pragma unroll
  for (int i = 0; i < 4; ++i) {
    int o = tid + (i << 8);
    int nl = o >> 5, kl = o & 31;
    Mt[((n0 + nl) << 9) + k0 + kl] = (f16)accv[i];
  }
}

// ---- prep: Wdt[n][512+k2] = sum_e Wv[k2][e]*Wdown[512+e][n] ----
__global__ __launch_bounds__(256) void prep_w2(const float* __restrict__ Wv,
                                               const float* __restrict__ Wdown,
                                               f16* __restrict__ Wdt) {
  __shared__ float vs[32][68];
  __shared__ float dsm[32][68];   // [n][e] transposed stage
  const int tid = threadIdx.x;
  const int n0 = (blockIdx.x & 15) << 5;
  const int k0 = (blockIdx.x >> 4) << 5;
  float accv[4] = {0.f, 0.f, 0.f, 0.f};
  for (int e0 = 0; e0 < 512; e0 += 64) {
    #pragma unroll
    for (int i = 0; i < 2; ++i) {
      int c = tid + (i << 8);
      int r = c >> 4;
      int e4 = (c & 15) << 2;
      *reinterpret_cast<float4*>(&vs[r][e4]) =
          *reinterpret_cast<const float4*>(Wv + ((k0 + r) << 9) + e0 + e4);
    }
    #pragma unroll
    for (int i = 0; i < 8; ++i) {
      int c = tid + (i << 8);
      int el = c >> 5;
      int nl = c & 31;
      dsm[nl][el] = Wdown[((512 + e0 + el) << 9) + n0 + nl];
    }
    __syncthreads();
    #pragma unroll
    for (int i = 0; i < 4; ++i) {
      int o = tid + (i << 8);
      int nl = o >> 5, kl = o & 31;
      float s = accv[i];
      #pragma unroll
      for (int e = 0; e < 64; e += 4) {
        float4 a  = *reinterpret_cast<const float4*>(&vs[kl][e]);
        float4 bq = *reinterpret_cast<const float4*>(&dsm[nl][e]);
        s += a.x * bq.x + a.y * bq.y + a.z * bq.z + a.w * bq.w;
      }
      accv[i] = s;
    }
    __syncthreads();
  }
  #pragma unroll
  for (int i = 0; i < 4; ++i) {
    int o = tid + (i << 8);
    int nl = o >> 5, kl = o & 31;
    Wdt[((n0 + nl) << 10) + 512 + k0 + kl] = (f16)accv[i];
  }
}

// ---- prep: Wdt[n][k] = Wdown[k][n], k<512 (transpose copy) ----
__global__ __launch_bounds__(256) void prep_copy(const float* __restrict__ Wdown,
                                                 f16* __restrict__ Wdt) {
  __shared__ float ts[32][33];
  const int tid = threadIdx.x;
  const int n0 = (blockIdx.x & 15) << 5;
  const int k0 = (blockIdx.x >> 4) << 5;
  #pragma unroll
  for (int i = 0; i < 4; ++i) {
    int c = tid + (i << 8);
    int r = c >> 5;
    int nl = c & 31;
    ts[r][nl] = Wdown[((k0 + r) << 9) + n0 + nl];
  }
  __syncthreads();
  #pragma unroll
  for (int i = 0; i < 4; ++i) {
    int c = tid + (i << 8);
    int nl = c >> 5;
    int kl = c & 31;
    Wdt[((n0 + nl) << 10) + k0 + kl] = (f16)ts[kl][nl];
  }
}

extern "C" void kernel_launch(void* const* d_in, const int* in_sizes, int n_in,
                              void* d_out, int out_size, void* d_ws, size_t ws_size,
                              hipStream_t stream) {
  const float* h   = (const float*)d_in[0];
  const float* enc = (const float*)d_in[1];
  const float* Wq  = (const float*)d_in[2];
  const float* Wk  = (const float*)d_in[3];
  const float* Wv  = (const float*)d_in[4];
  const float* Wd  = (const float*)d_in[5];
  float* out = (float*)d_out;

  f16* Mt  = (f16*)d_ws;            // 512*512 f16 = 512KB
  f16* Wdt = Mt + 512 * 512;        // 512*1024 f16 = 1MB

  (void)hipFuncSetAttribute(reinterpret_cast<const void*>(fused_attn),
                            hipFuncAttributeMaxDynamicSharedMemorySize, LDS_TOTAL);

  prep_mt<<<256, 256, 0, stream>>>(Wq, Wk, Mt);
  prep_w2<<<256, 256, 0, stream>>>(Wv, Wd, Wdt);
  prep_copy<<<256, 256, 0, stream>>>(Wd, Wdt);
  fused_attn<<<B_TOT / NBATCH, THREADS, LDS_TOTAL, stream>>>(h, enc, Mt, Wdt, out);
}

// Round 2
// 189.734 us; speedup vs baseline: 1.7296x; 1.7296x over previous
//
#include <hip/hip_runtime.h>
#include <hip/hip_fp16.h>

// out = h@Wd1 + (softmax(h@M@e^T)@e)@W2,  M=Wq@Wk^T, W2=Wv@Wd2 (folded on device).
// Round-2 structure: 1024-thr block (16 waves, 4/SIMD), LDS = H panel (64KB) +
// T/U panel (64KB). B-operands (Mt, Wdt) loaded straight from global in MFMA
// fragment layout (no LDS staging). Wave tile = 64 rows x 32 cols, acc[4][2].

#define B_TOT   16384
#define TQn     2
#define TKn     5
#define NB      32            // batches per block
#define ROWS    64            // NB * TQn
#define THREADS 1024
#define WCOLS   32

typedef _Float16 f16;
typedef _Float16 f16x8 __attribute__((ext_vector_type(8)));
typedef _Float16 f16x4 __attribute__((ext_vector_type(4)));
typedef float    f32x4 __attribute__((ext_vector_type(4)));

#define HPAN 0
#define TPAN 65536
#define LDS_TOTAL 131072

#define MFMA16(a, b, c) __builtin_amdgcn_mfma_f32_16x16x32_f16(a, b, c, 0, 0, 0)

__global__ __launch_bounds__(THREADS, 4) void fused_attn(
    const float* __restrict__ hptr, const float* __restrict__ eptr,
    const f16* __restrict__ Mt, const f16* __restrict__ Wdt,
    float* __restrict__ outp)
{
  extern __shared__ char smem[];
  const int tid  = threadIdx.x;
  const int lane = tid & 63;
  const int w    = tid >> 6;
  const int g    = lane >> 4;
  const int l15  = lane & 15;
  const int b0   = blockIdx.x * NB;
  const int n0   = w * WCOLS;
  const int xsw  = (l15 & 7) << 4;   // swizzle const for fragment reads (row&7 == l15&7)

  // ---- stage H: fp32 global -> f16 LDS panel (swizzled) ----
  #pragma unroll
  for (int i = 0; i < 8; ++i) {
    int c   = tid + THREADS * i;        // 8192 float4 chunks = 64 rows x 128
    int row = c >> 7;
    int k4  = c & 127;
    int tq  = row & 1;
    int b   = b0 + (row >> 1);
    float4 v = *reinterpret_cast<const float4*>(
        hptr + ((size_t)(tq * B_TOT + b) << 9) + (k4 << 2));
    f16x4 p;
    p[0] = (f16)v.x; p[1] = (f16)v.y; p[2] = (f16)v.z; p[3] = (f16)v.w;
    *reinterpret_cast<f16x4*>(smem + HPAN + row * 1024 +
                              (((k4 << 3)) ^ ((row & 7) << 4))) = p;
  }

  // GEMM1 B fragment base: Mt[n][k], row stride 512 f16. lane holds n=n0+l15 (+16*fn), k=g*8..+7
  const f16* bpM = Mt + (size_t)(n0 + l15) * 512 + (g << 3);
  f16x8 bc0 = *reinterpret_cast<const f16x8*>(bpM);
  f16x8 bc1 = *reinterpret_cast<const f16x8*>(bpM + 16 * 512);

  __syncthreads();   // H staged

  // ---- GEMM1: T[64x512] = H @ M (wave owns 32 cols) ----
  f32x4 accT[4][2];
  #pragma unroll
  for (int fm = 0; fm < 4; ++fm) {
    accT[fm][0] = (f32x4){0.f, 0.f, 0.f, 0.f};
    accT[fm][1] = (f32x4){0.f, 0.f, 0.f, 0.f};
  }
  for (int kt = 0; kt < 16; ++kt) {
    f16x8 af[4];
    #pragma unroll
    for (int fm = 0; fm < 4; ++fm) {
      int row = (fm << 4) + l15;
      af[fm] = *reinterpret_cast<const f16x8*>(
          smem + HPAN + row * 1024 + (((kt << 6) + (g << 4)) ^ xsw));
    }
    if (kt < 15) {
      f16x8 bn0 = *reinterpret_cast<const f16x8*>(bpM + (kt + 1) * 32);
      f16x8 bn1 = *reinterpret_cast<const f16x8*>(bpM + 16 * 512 + (kt + 1) * 32);
      #pragma unroll
      for (int fm = 0; fm < 4; ++fm) {
        accT[fm][0] = MFMA16(af[fm], bc0, accT[fm][0]);
        accT[fm][1] = MFMA16(af[fm], bc1, accT[fm][1]);
      }
      bc0 = bn0; bc1 = bn1;
    } else {
      #pragma unroll
      for (int fm = 0; fm < 4; ++fm) {
        accT[fm][0] = MFMA16(af[fm], bc0, accT[fm][0]);
        accT[fm][1] = MFMA16(af[fm], bc1, accT[fm][1]);
      }
    }
  }

  // ---- T -> LDS f16 (C/D map: row=(lane>>4)*4+reg, col=lane&15) ----
  #pragma unroll
  for (int fm = 0; fm < 4; ++fm)
    #pragma unroll
    for (int fn = 0; fn < 2; ++fn)
      #pragma unroll
      for (int r = 0; r < 4; ++r) {
        int row = (fm << 4) + (g << 2) + r;
        int col = n0 + (fn << 4) + l15;
        *reinterpret_cast<f16*>(smem + TPAN + row * 1024 +
                                (((col << 1)) ^ ((row & 7) << 4))) = (f16)accT[fm][fn][r];
      }
  __syncthreads();   // all T visible

  // ---- softmax + u = att@e (fp32), 2 batches per wave ----
  for (int bi = 0; bi < 2; ++bi) {
    const int bl = (w << 1) + bi;
    const int b  = b0 + bl;
    float ev[TKn][8];
    #pragma unroll
    for (int j = 0; j < TKn; ++j) {
      const float4* p4 = reinterpret_cast<const float4*>(
          eptr + ((size_t)(j * B_TOT + b) << 9) + (lane << 3));
      float4 u0 = p4[0], u1 = p4[1];
      ev[j][0] = u0.x; ev[j][1] = u0.y; ev[j][2] = u0.z; ev[j][3] = u0.w;
      ev[j][4] = u1.x; ev[j][5] = u1.y; ev[j][6] = u1.z; ev[j][7] = u1.w;
    }
    float tv[TQn][8];
    #pragma unroll
    for (int i = 0; i < TQn; ++i) {
      int row = (bl << 1) + i;
      f16x8 tf = *reinterpret_cast<const f16x8*>(
          smem + TPAN + row * 1024 + (((lane << 4)) ^ ((row & 7) << 4)));
      #pragma unroll
      for (int m = 0; m < 8; ++m) tv[i][m] = (float)tf[m];
    }
    float p[TQn][TKn];
    #pragma unroll
    for (int i = 0; i < TQn; ++i)
      #pragma unroll
      for (int j = 0; j < TKn; ++j) {
        float s = 0.f;
        #pragma unroll
        for (int m = 0; m < 8; ++m) s += tv[i][m] * ev[j][m];
        p[i][j] = s;
      }
    #pragma unroll
    for (int d = 1; d < 64; d <<= 1)
      #pragma unroll
      for (int i = 0; i < TQn; ++i)
        #pragma unroll
        for (int j = 0; j < TKn; ++j)
          p[i][j] += __shfl_xor(p[i][j], d, 64);
    #pragma unroll
    for (int i = 0; i < TQn; ++i) {
      float mx = p[i][0];
      #pragma unroll
      for (int j = 1; j < TKn; ++j) mx = fmaxf(mx, p[i][j]);
      float sum = 0.f;
      #pragma unroll
      for (int j = 0; j < TKn; ++j) { float e = __expf(p[i][j] - mx); p[i][j] = e; sum += e; }
      float rs = 1.0f / sum;
      int row = (bl << 1) + i;
      f16x8 uv;
      #pragma unroll
      for (int m = 0; m < 8; ++m) {
        float s = 0.f;
        #pragma unroll
        for (int j = 0; j < TKn; ++j) s += p[i][j] * ev[j][m];
        uv[m] = (f16)(s * rs);
      }
      *reinterpret_cast<f16x8*>(
          smem + TPAN + row * 1024 + (((lane << 4)) ^ ((row & 7) << 4))) = uv;
    }
  }
  __syncthreads();   // all U visible

  // ---- GEMM2: OUT[64x512] = [H|U] @ Wdt  (K=1024; k<512 from HPAN, k>=512 from TPAN) ----
  const f16* bpW = Wdt + (size_t)(n0 + l15) * 1024 + (g << 3);
  bc0 = *reinterpret_cast<const f16x8*>(bpW);
  bc1 = *reinterpret_cast<const f16x8*>(bpW + 16 * 1024);
  f32x4 accP[4][2];
  #pragma unroll
  for (int fm = 0; fm < 4; ++fm) {
    accP[fm][0] = (f32x4){0.f, 0.f, 0.f, 0.f};
    accP[fm][1] = (f32x4){0.f, 0.f, 0.f, 0.f};
  }
  for (int kt = 0; kt < 32; ++kt) {
    char* ab = smem + ((kt >> 4) << 16);   // HPAN for kt<16, TPAN for kt>=16
    f16x8 af[4];
    #pragma unroll
    for (int fm = 0; fm < 4; ++fm) {
      int row = (fm << 4) + l15;
      af[fm] = *reinterpret_cast<const f16x8*>(
          ab + row * 1024 + ((((kt & 15) << 6) + (g << 4)) ^ xsw));
    }
    if (kt < 31) {
      f16x8 bn0 = *reinterpret_cast<const f16x8*>(bpW + (kt + 1) * 32);
      f16x8 bn1 = *reinterpret_cast<const f16x8*>(bpW + 16 * 1024 + (kt + 1) * 32);
      #pragma unroll
      for (int fm = 0; fm < 4; ++fm) {
        accP[fm][0] = MFMA16(af[fm], bc0, accP[fm][0]);
        accP[fm][1] = MFMA16(af[fm], bc1, accP[fm][1]);
      }
      bc0 = bn0; bc1 = bn1;
    } else {
      #pragma unroll
      for (int fm = 0; fm < 4; ++fm) {
        accP[fm][0] = MFMA16(af[fm], bc0, accP[fm][0]);
        accP[fm][1] = MFMA16(af[fm], bc1, accP[fm][1]);
      }
    }
  }

  // ---- epilogue: fp32 store ----
  #pragma unroll
  for (int fm = 0; fm < 4; ++fm)
    #pragma unroll
    for (int fn = 0; fn < 2; ++fn)
      #pragma unroll
      for (int r = 0; r < 4; ++r) {
        int row = (fm << 4) + (g << 2) + r;
        int col = n0 + (fn << 4) + l15;
        int tq  = row & 1;
        int b   = b0 + (row >> 1);
        outp[((size_t)(tq * B_TOT + b) << 9) + col] = accP[fm][fn][r];
      }
}

// ---- prep (one kernel, 3 block-ranges): Mt[n][k]=(WqWk^T)[k][n];
//      Wdt[n][k<512]=Wdown[k][n]; Wdt[n][512+k2]=(Wv@Wd2)[k2][n] ----
__global__ __launch_bounds__(256) void prep_all(
    const float* __restrict__ Wq, const float* __restrict__ Wk,
    const float* __restrict__ Wv, const float* __restrict__ Wdown,
    f16* __restrict__ Mt, f16* __restrict__ Wdt)
{
  __shared__ float sA[32][68];
  __shared__ float sB[32][68];
  const int tid = threadIdx.x;
  const int bx  = blockIdx.x;

  if (bx < 512) {
    // GEMM-fold paths: bx<256 -> Mt; 256..511 -> W2 half of Wdt
    const bool mt  = (bx < 256);
    const int  bb  = mt ? bx : bx - 256;
    const int  n0  = (bb & 15) << 5;
    const int  k0  = (bb >> 4) << 5;
    float accv[4] = {0.f, 0.f, 0.f, 0.f};
    for (int e0 = 0; e0 < 512; e0 += 64) {
      if (mt) {
        #pragma unroll
        for (int i = 0; i < 2; ++i) {
          int c = tid + (i << 8);
          int r = c >> 4, e4 = (c & 15) << 2;
          *reinterpret_cast<float4*>(&sA[r][e4]) =
              *reinterpret_cast<const float4*>(Wq + ((k0 + r) << 9) + e0 + e4);
          *reinterpret_cast<float4*>(&sB[r][e4]) =
              *reinterpret_cast<const float4*>(Wk + ((n0 + r) << 9) + e0 + e4);
        }
      } else {
        #pragma unroll
        for (int i = 0; i < 2; ++i) {
          int c = tid + (i << 8);
          int r = c >> 4, e4 = (c & 15) << 2;
          *reinterpret_cast<float4*>(&sA[r][e4]) =
              *reinterpret_cast<const float4*>(Wv + ((k0 + r) << 9) + e0 + e4);
        }
        #pragma unroll
        for (int i = 0; i < 8; ++i) {
          int c = tid + (i << 8);
          int el = c >> 5, nl = c & 31;
          sB[nl][el] = Wdown[((512 + e0 + el) << 9) + n0 + nl];
        }
      }
      __syncthreads();
      #pragma unroll
      for (int i = 0; i < 4; ++i) {
        int o = tid + (i << 8);
        int nl = o >> 5, kl = o & 31;
        float s = accv[i];
        #pragma unroll
        for (int e = 0; e < 64; e += 4) {
          float4 a  = *reinterpret_cast<const float4*>(&sA[kl][e]);
          float4 bq = *reinterpret_cast<const float4*>(&sB[nl][e]);
          s += a.x * bq.x + a.y * bq.y + a.z * bq.z + a.w * bq.w;
        }
        accv[i] = s;
      }
      __syncthreads();
    }
    #pragma unroll
    for (int i = 0; i < 4; ++i) {
      int o = tid + (i << 8);
      int nl = o >> 5, kl = o & 31;
      if (mt) Mt[((n0 + nl) << 9) + k0 + kl] = (f16)accv[i];
      else    Wdt[((n0 + nl) << 10) + 512 + k0 + kl] = (f16)accv[i];
    }
  } else {
    // transpose-copy: Wdt[n][k] = Wdown[k][n], k<512
    const int bb = bx - 512;
    const int n0 = (bb & 15) << 5;
    const int k0 = (bb >> 4) << 5;
    #pragma unroll
    for (int i = 0; i < 4; ++i) {
      int c = tid + (i << 8);
      int r = c >> 5, nl = c & 31;
      sA[r][nl] = Wdown[((k0 + r) << 9) + n0 + nl];
    }
    __syncthreads();
    #pragma unroll
    for (int i = 0; i < 4; ++i) {
      int c = tid + (i << 8);
      int nl = c >> 5, kl = c & 31;
      Wdt[((n0 + nl) << 10) + k0 + kl] = (f16)sA[kl][nl];
    }
  }
}

extern "C" void kernel_launch(void* const* d_in, const int* in_sizes, int n_in,
                              void* d_out, int out_size, void* d_ws, size_t ws_size,
                              hipStream_t stream) {
  const float* h   = (const float*)d_in[0];
  const float* enc = (const float*)d_in[1];
  const float* Wq  = (const float*)d_in[2];
  const float* Wk  = (const float*)d_in[3];
  const float* Wv  = (const float*)d_in[4];
  const float* Wd  = (const float*)d_in[5];
  float* out = (float*)d_out;

  f16* Mt  = (f16*)d_ws;            // 512x512 f16
  f16* Wdt = Mt + 512 * 512;        // 512x1024 f16

  (void)hipFuncSetAttribute(reinterpret_cast<const void*>(fused_attn),
                            hipFuncAttributeMaxDynamicSharedMemorySize, LDS_TOTAL);

  prep_all<<<768, 256, 0, stream>>>(Wq, Wk, Wv, Wd, Mt, Wdt);
  fused_attn<<<B_TOT / NB, THREADS, LDS_TOTAL, stream>>>(h, enc, Mt, Wdt, out);
}